// Round 8
// baseline (1837.620 us; speedup 1.0000x reference)
//
#include <hip/hip_runtime.h>
#include <hip/hip_bf16.h>
#include <math.h>

// Problem constants
#define D_MODEL 256
#define DEPTH 2
#define D_INNER 512
#define D_STATE 16
#define D_CONV 4
#define DT_RANK 16
#define BATCH 2
#define SEQLEN 2048
#define MROWS (BATCH * SEQLEN)   // 4096

#define CCH 128   // chunks per batch-sequence
#define LCH 16    // rows per chunk

#define NBLK 512  // grid size; 2 blocks/CU co-resident by __launch_bounds__(256,2)

typedef __attribute__((ext_vector_type(8))) short bf16x8;
typedef __attribute__((ext_vector_type(4))) float f32x4;

__device__ __forceinline__ float silu(float v) {
    return v / (1.0f + __expf(-v));
}

__device__ __forceinline__ ushort f2bf(float f) {
    union { float f; unsigned u; } v; v.f = f;
    unsigned r = v.u + 0x7FFFu + ((v.u >> 16) & 1u);
    return (ushort)(r >> 16);
}

__device__ __forceinline__ float bf2f(ushort u) {
    union { unsigned u; float f; } v; v.u = ((unsigned)u) << 16;
    return v.f;
}

// ---------------------------------------------------------------------------
// Grid-wide barrier: sense-reversing, device-scope atomics. bar[0]=count,
// bar[1]=generation. All NBLK blocks are co-resident (capacity argument:
// launch_bounds(256,2) => 2 blocks/CU * 256 CUs == NBLK), so spinning is safe.
// __threadfence() at agent scope emits L2 writeback/invalidate on gfx950, so
// ordinary global stores before the barrier are visible after it (cross-XCD
// via LLC).
// ---------------------------------------------------------------------------
__device__ __forceinline__ void gbar(int* bar)
{
    __syncthreads();
    if (threadIdx.x == 0) {
        __threadfence();
        int g = __hip_atomic_load(bar + 1, __ATOMIC_RELAXED, __HIP_MEMORY_SCOPE_AGENT);
        int n = __hip_atomic_fetch_add(bar, 1, __ATOMIC_ACQ_REL, __HIP_MEMORY_SCOPE_AGENT);
        if (n == NBLK - 1) {
            __hip_atomic_store(bar, 0, __ATOMIC_RELAXED, __HIP_MEMORY_SCOPE_AGENT);
            __hip_atomic_fetch_add(bar + 1, 1, __ATOMIC_RELEASE, __HIP_MEMORY_SCOPE_AGENT);
        } else {
            while (__hip_atomic_load(bar + 1, __ATOMIC_ACQUIRE, __HIP_MEMORY_SCOPE_AGENT) == g)
                __builtin_amdgcn_s_sleep(2);
        }
        __threadfence();
    }
    __syncthreads();
}

struct Params {
    const float* x;
    const float* lnw;  const float* lnb;
    const float* ipw;  const float* cw;   const float* cb;
    const float* xpw;  const float* dpw;  const float* dpb;
    const float* alog; const float* dpar; const float* opw;
    float* out;
    int*    bar;    // [2] grid barrier state (memset to 0 on stream pre-launch)
    // workspace
    float*  xz;     // [4096][1024] f32
    ushort* xcB;    // [4096][512] bf16
    float*  dbl;    // [4096][48] f32
    float*  Ssum;   // [2][128][16][512] f32
    float*  sdsum;  // [2][128][512] f32
    ushort* yyB;    // [4096][512] bf16
    float*  xbuf;   // [4096][256] f32
    ushort* ipwB;   // [2][1024][256] bf16
    ushort* xpwB;   // [2][48][512] bf16
    ushort* opwB;   // [2][256][512] bf16
};

#define XS_STR 260   // f32 stride for 16x256 LN tile (pad vs 32 banks)
#define HS_STR 264   // ushort stride for 16x256 bf16 tile (16B aligned rows)

__global__ __launch_bounds__(256, 2) void mamba_fused(Params p)
{
    const int t   = threadIdx.x;
    const int bid = blockIdx.x;
    const int lane = t & 63;
    const int w    = t >> 6;
    const int l15  = lane & 15;
    const int quad = lane >> 4;

    __shared__ float  xs[16 * XS_STR];           // 16640 B
    __shared__ ushort hs[16 * HS_STR];           // 8448 B

    // ---------------- Phase 0: weight cvt f32 -> bf16 ----------------
    {
        size_t tid = (size_t)bid * 256 + t;
        {   // ipw: 2*1024*256 elems = 131072 float4 (== grid threads)
            float4 v = ((const float4*)p.ipw)[tid];
            ushort4 o = { f2bf(v.x), f2bf(v.y), f2bf(v.z), f2bf(v.w) };
            ((ushort4*)p.ipwB)[tid] = o;
        }
        if (tid < 12288) {   // xpw: 2*48*512/4
            float4 v = ((const float4*)p.xpw)[tid];
            ushort4 o = { f2bf(v.x), f2bf(v.y), f2bf(v.z), f2bf(v.w) };
            ((ushort4*)p.xpwB)[tid] = o;
        }
        if (tid < 65536) {   // opw: 2*256*512/4
            float4 v = ((const float4*)p.opw)[tid];
            ushort4 o = { f2bf(v.x), f2bf(v.y), f2bf(v.z), f2bf(v.w) };
            ((ushort4*)p.opwB)[tid] = o;
        }
    }
    gbar(p.bar);

    for (int lyr = 0; lyr < DEPTH; lyr++) {
        const float*  xin   = (lyr == 0) ? p.x : p.xbuf;
        float*        xout  = (lyr == DEPTH - 1) ? p.out : p.xbuf;
        const float*  lnwL  = p.lnw + lyr * D_MODEL;
        const float*  lnbL  = p.lnb + lyr * D_MODEL;
        const ushort* ipwL  = p.ipwB + (size_t)lyr * 2 * D_INNER * D_MODEL;
        const float*  cwL   = p.cw  + (size_t)lyr * D_INNER * D_CONV;
        const float*  cbL   = p.cb  + lyr * D_INNER;
        const ushort* xpwL  = p.xpwB + (size_t)lyr * 48 * D_INNER;
        const float*  dpwL  = p.dpw + (size_t)lyr * D_INNER * DT_RANK;
        const float*  dpbL  = p.dpb + lyr * D_INNER;
        const float*  alogL = p.alog + (size_t)lyr * D_INNER * D_STATE;
        const float*  dparL = p.dpar + lyr * D_INNER;
        const ushort* opwL  = p.opwB + (size_t)lyr * D_MODEL * D_INNER;

        // ---------- Phase A: LayerNorm (in-block) + in_proj MFMA ----------
        {
            int mt = bid >> 1, nh = bid & 1;
            int m0 = mt * 16;
            // load 16x256 x-tile into LDS (coalesced float4)
            #pragma unroll
            for (int i = 0; i < 4; i++) {
                int idx = t + 256 * i;                 // float4 index
                int r = idx >> 6, c = (idx & 63) * 4;
                float4 v = *(const float4*)(xin + (size_t)(m0 + r) * D_MODEL + c);
                *(float4*)&xs[r * XS_STR + c] = v;
            }
            __syncthreads();
            // per-row stats: 16 threads per row
            int r = t >> 4, ci = t & 15;
            float s = 0.f, sq = 0.f;
            #pragma unroll
            for (int k = 0; k < 16; k++) {
                float v = xs[r * XS_STR + ci + 16 * k];
                s += v; sq += v * v;
            }
            #pragma unroll
            for (int off = 1; off < 16; off <<= 1) {
                s  += __shfl_xor(s, off, 16);
                sq += __shfl_xor(sq, off, 16);
            }
            float mu  = s * (1.0f / 256.f);
            float var = sq * (1.0f / 256.f) - mu * mu;
            float rst = rsqrtf(var + 1e-5f);
            #pragma unroll
            for (int k = 0; k < 16; k++) {
                int c = ci + 16 * k;
                float v = (xs[r * XS_STR + c] - mu) * rst * lnwL[c] + lnbL[c];
                hs[r * HS_STR + c] = f2bf(v);
            }
            __syncthreads();
            // MFMA: 4 waves x NF=8 -> block covers 512 n (nh selects half)
            int nbase = nh * 512 + w * 128;
            f32x4 acc[8];
            #pragma unroll
            for (int f = 0; f < 8; f++) acc[f] = (f32x4){0.f,0.f,0.f,0.f};
            for (int k0 = 0; k0 < D_MODEL; k0 += 32) {
                bf16x8 af = *(const bf16x8*)&hs[l15 * HS_STR + quad * 8 + k0];
                #pragma unroll
                for (int f = 0; f < 8; f++) {
                    const ushort* bp = ipwL + (size_t)(nbase + f * 16 + l15) * D_MODEL + quad * 8 + k0;
                    bf16x8 bw = *(const bf16x8*)bp;
                    acc[f] = __builtin_amdgcn_mfma_f32_16x16x32_bf16(af, bw, acc[f], 0, 0, 0);
                }
            }
            #pragma unroll
            for (int f = 0; f < 8; f++) {
                int n = nbase + f * 16 + l15;
                #pragma unroll
                for (int r2 = 0; r2 < 4; r2++)
                    p.xz[(size_t)(m0 + quad * 4 + r2) * (2 * D_INNER) + n] = acc[f][r2];
            }
        }
        gbar(p.bar);

        // ---------- Phase B: causal conv(4) + SiLU -> xcB bf16 ----------
        {
            int r0 = bid * 8 + w * 2;
            #pragma unroll
            for (int rr = 0; rr < 2; rr++) {
                int row = r0 + rr;
                int l = row & (SEQLEN - 1);
                #pragma unroll
                for (int dd = 0; dd < 8; dd++) {
                    int d = dd * 64 + lane;
                    const float* xp = p.xz + (size_t)row * (2 * D_INNER) + d;
                    float s = cbL[d];
                    if (l >= 3) s = fmaf(cwL[d * 4 + 0], xp[-3 * 2 * D_INNER], s);
                    if (l >= 2) s = fmaf(cwL[d * 4 + 1], xp[-2 * 2 * D_INNER], s);
                    if (l >= 1) s = fmaf(cwL[d * 4 + 2], xp[-1 * 2 * D_INNER], s);
                    s = fmaf(cwL[d * 4 + 3], xp[0], s);
                    p.xcB[(size_t)row * D_INNER + d] = f2bf(silu(s));
                }
            }
        }
        gbar(p.bar);

        // ---------- Phase C: x_proj MFMA (768 wave-tiles) ----------
        {
            int gw = bid * 4 + w;
            if (gw < 768) {
                int mt = gw / 3, nt = gw - mt * 3;
                int m0 = mt * 16;
                f32x4 acc = (f32x4){0.f,0.f,0.f,0.f};
                for (int k0 = 0; k0 < D_INNER; k0 += 32) {
                    bf16x8 af = *(const bf16x8*)(p.xcB + (size_t)(m0 + l15) * D_INNER + quad * 8 + k0);
                    bf16x8 bw = *(const bf16x8*)(xpwL + (size_t)(nt * 16 + l15) * D_INNER + quad * 8 + k0);
                    acc = __builtin_amdgcn_mfma_f32_16x16x32_bf16(af, bw, acc, 0, 0, 0);
                }
                int n = nt * 16 + l15;
                #pragma unroll
                for (int r2 = 0; r2 < 4; r2++)
                    p.dbl[(size_t)(m0 + quad * 4 + r2) * 48 + n] = acc[r2];
            }
        }
        gbar(p.bar);

        // ---------- Phase D: scan_sum (delta inline) ----------
        {
            int ct = bid & 31, b = (bid >> 5) & 1, dt2 = bid >> 6;
            int d = dt2 * 64 + lane;
            int c = ct * 4 + w;
            int row0 = b * SEQLEN + c * LCH;
            float a[16], wdp[16];
            #pragma unroll
            for (int n = 0; n < 16; n++) a[n] = -__expf(alogL[(size_t)d * 16 + n]);
            *(float4*)&wdp[0]  = *(const float4*)(dpwL + (size_t)d * 16 + 0);
            *(float4*)&wdp[4]  = *(const float4*)(dpwL + (size_t)d * 16 + 4);
            *(float4*)&wdp[8]  = *(const float4*)(dpwL + (size_t)d * 16 + 8);
            *(float4*)&wdp[12] = *(const float4*)(dpwL + (size_t)d * 16 + 12);
            float bias = dpbL[d];
            float h[16];
            #pragma unroll
            for (int n = 0; n < 16; n++) h[n] = 0.f;
            float sd = 0.f;
            for (int j = 0; j < LCH; j++) {
                int row = row0 + j;
                const float* dp = p.dbl + (size_t)row * 48;
                float dtv[16], Bv[16];
                *(float4*)&dtv[0]  = *(const float4*)(dp + 0);
                *(float4*)&dtv[4]  = *(const float4*)(dp + 4);
                *(float4*)&dtv[8]  = *(const float4*)(dp + 8);
                *(float4*)&dtv[12] = *(const float4*)(dp + 12);
                *(float4*)&Bv[0]   = *(const float4*)(dp + 16);
                *(float4*)&Bv[4]   = *(const float4*)(dp + 20);
                *(float4*)&Bv[8]   = *(const float4*)(dp + 24);
                *(float4*)&Bv[12]  = *(const float4*)(dp + 28);
                float dot = bias;
                #pragma unroll
                for (int r2 = 0; r2 < 16; r2++) dot = fmaf(dtv[r2], wdp[r2], dot);
                float dl = (dot > 20.f) ? dot : log1pf(__expf(dot));
                float xv = bf2f(p.xcB[(size_t)row * D_INNER + d]);
                float u = dl * xv;
                sd += dl;
                #pragma unroll
                for (int n = 0; n < 16; n++)
                    h[n] = fmaf(__expf(dl * a[n]), h[n], Bv[n] * u);
            }
            size_t sbase = ((size_t)(b * CCH + c) * 16) * D_INNER + d;
            #pragma unroll
            for (int n = 0; n < 16; n++) p.Ssum[sbase + (size_t)n * D_INNER] = h[n];
            p.sdsum[(size_t)(b * CCH + c) * D_INNER + d] = sd;
        }
        gbar(p.bar);

        // ---------- Phase E: scan_comb (exclusive prefix over chunks) ----------
        if (bid < 64) {
            int dt2 = bid & 1;
            int n   = (bid >> 1) & 15;
            int b   = bid >> 5;
            int d   = dt2 * 256 + t;
            float a = -__expf(alogL[(size_t)d * 16 + n]);
            float hi = 0.f;
            #pragma unroll 4
            for (int c = 0; c < CCH; c++) {
                size_t idx = ((size_t)(b * CCH + c) * 16 + n) * D_INNER + d;
                float s  = p.Ssum[idx];
                float sd = p.sdsum[(size_t)(b * CCH + c) * D_INNER + d];
                p.Ssum[idx] = hi;
                hi = fmaf(__expf(a * sd), hi, s);
            }
        }
        gbar(p.bar);

        // ---------- Phase F: scan_emit (delta inline, gated bf16 out) ----------
        {
            int ct = bid & 31, b = (bid >> 5) & 1, dt2 = bid >> 6;
            int d = dt2 * 64 + lane;
            int c = ct * 4 + w;
            int row0 = b * SEQLEN + c * LCH;
            float a[16], wdp[16];
            #pragma unroll
            for (int n = 0; n < 16; n++) a[n] = -__expf(alogL[(size_t)d * 16 + n]);
            *(float4*)&wdp[0]  = *(const float4*)(dpwL + (size_t)d * 16 + 0);
            *(float4*)&wdp[4]  = *(const float4*)(dpwL + (size_t)d * 16 + 4);
            *(float4*)&wdp[8]  = *(const float4*)(dpwL + (size_t)d * 16 + 8);
            *(float4*)&wdp[12] = *(const float4*)(dpwL + (size_t)d * 16 + 12);
            float bias = dpbL[d];
            float h[16];
            size_t sbase = ((size_t)(b * CCH + c) * 16) * D_INNER + d;
            #pragma unroll
            for (int n = 0; n < 16; n++) h[n] = p.Ssum[sbase + (size_t)n * D_INNER];
            float Dd = dparL[d];
            for (int j = 0; j < LCH; j++) {
                int row = row0 + j;
                const float* dp = p.dbl + (size_t)row * 48;
                float dtv[16], Bv[16], Cv[16];
                *(float4*)&dtv[0]  = *(const float4*)(dp + 0);
                *(float4*)&dtv[4]  = *(const float4*)(dp + 4);
                *(float4*)&dtv[8]  = *(const float4*)(dp + 8);
                *(float4*)&dtv[12] = *(const float4*)(dp + 12);
                *(float4*)&Bv[0]   = *(const float4*)(dp + 16);
                *(float4*)&Bv[4]   = *(const float4*)(dp + 20);
                *(float4*)&Bv[8]   = *(const float4*)(dp + 24);
                *(float4*)&Bv[12]  = *(const float4*)(dp + 28);
                *(float4*)&Cv[0]   = *(const float4*)(dp + 32);
                *(float4*)&Cv[4]   = *(const float4*)(dp + 36);
                *(float4*)&Cv[8]   = *(const float4*)(dp + 40);
                *(float4*)&Cv[12]  = *(const float4*)(dp + 44);
                float dot = bias;
                #pragma unroll
                for (int r2 = 0; r2 < 16; r2++) dot = fmaf(dtv[r2], wdp[r2], dot);
                float dl = (dot > 20.f) ? dot : log1pf(__expf(dot));
                float xv = bf2f(p.xcB[(size_t)row * D_INNER + d]);
                float z  = p.xz[(size_t)row * (2 * D_INNER) + D_INNER + d];
                float u = dl * xv;
                float y0 = 0.f, y1 = 0.f, y2 = 0.f, y3 = 0.f;
                #pragma unroll
                for (int n = 0; n < 16; n += 4) {
                    h[n + 0] = fmaf(__expf(dl * a[n + 0]), h[n + 0], Bv[n + 0] * u);
                    h[n + 1] = fmaf(__expf(dl * a[n + 1]), h[n + 1], Bv[n + 1] * u);
                    h[n + 2] = fmaf(__expf(dl * a[n + 2]), h[n + 2], Bv[n + 2] * u);
                    h[n + 3] = fmaf(__expf(dl * a[n + 3]), h[n + 3], Bv[n + 3] * u);
                    y0 = fmaf(h[n + 0], Cv[n + 0], y0);
                    y1 = fmaf(h[n + 1], Cv[n + 1], y1);
                    y2 = fmaf(h[n + 2], Cv[n + 2], y2);
                    y3 = fmaf(h[n + 3], Cv[n + 3], y3);
                }
                float y = (y0 + y1) + (y2 + y3) + xv * Dd;
                p.yyB[(size_t)row * D_INNER + d] = f2bf(y * silu(z));
            }
        }
        gbar(p.bar);

        // ---------- Phase G: out_proj MFMA + residual ----------
        {
            int mt = bid >> 1, nh = bid & 1;
            int m0 = mt * 16;
            int nbase = nh * 128 + w * 32;
            f32x4 acc[2];
            acc[0] = (f32x4){0.f,0.f,0.f,0.f};
            acc[1] = (f32x4){0.f,0.f,0.f,0.f};
            for (int k0 = 0; k0 < D_INNER; k0 += 32) {
                bf16x8 af = *(const bf16x8*)(p.yyB + (size_t)(m0 + l15) * D_INNER + quad * 8 + k0);
                #pragma unroll
                for (int f = 0; f < 2; f++) {
                    const ushort* bp = opwL + (size_t)(nbase + f * 16 + l15) * D_INNER + quad * 8 + k0;
                    bf16x8 bw = *(const bf16x8*)bp;
                    acc[f] = __builtin_amdgcn_mfma_f32_16x16x32_bf16(af, bw, acc[f], 0, 0, 0);
                }
            }
            #pragma unroll
            for (int f = 0; f < 2; f++) {
                int n = nbase + f * 16 + l15;
                #pragma unroll
                for (int r2 = 0; r2 < 4; r2++) {
                    int row = m0 + quad * 4 + r2;
                    xout[(size_t)row * D_MODEL + n] =
                        acc[f][r2] + xin[(size_t)row * D_MODEL + n];
                }
            }
        }
        if (lyr != DEPTH - 1) gbar(p.bar);
    }
}

// ---------------------------------------------------------------------------
// Launch
// ---------------------------------------------------------------------------
extern "C" void kernel_launch(void* const* d_in, const int* in_sizes, int n_in,
                              void* d_out, int out_size, void* d_ws, size_t ws_size,
                              hipStream_t stream)
{
    Params prm;
    prm.x    = (const float*)d_in[0];
    prm.lnw  = (const float*)d_in[1];
    prm.lnb  = (const float*)d_in[2];
    prm.ipw  = (const float*)d_in[3];
    prm.cw   = (const float*)d_in[4];
    prm.cb   = (const float*)d_in[5];
    prm.xpw  = (const float*)d_in[6];
    prm.dpw  = (const float*)d_in[7];
    prm.dpb  = (const float*)d_in[8];
    prm.alog = (const float*)d_in[9];
    prm.dpar = (const float*)d_in[10];
    prm.opw  = (const float*)d_in[11];
    prm.out  = (float*)d_out;

    char* p = (char*)d_ws;
    auto alloc = [&](size_t bytes) { char* r = p; p += (bytes + 255) & ~(size_t)255; return r; };
    prm.bar   = (int*)alloc(256);   // barrier state (count, generation)
    prm.xz    = (float*)alloc((size_t)MROWS * 2 * D_INNER * 4);
    prm.xcB   = (ushort*)alloc((size_t)MROWS * D_INNER * 2);
    prm.dbl   = (float*)alloc((size_t)MROWS * 48 * 4);
    prm.Ssum  = (float*)alloc((size_t)BATCH * CCH * 16 * D_INNER * 4);
    prm.sdsum = (float*)alloc((size_t)BATCH * CCH * D_INNER * 4);
    prm.yyB   = (ushort*)alloc((size_t)MROWS * D_INNER * 2);
    prm.xbuf  = (float*)alloc((size_t)MROWS * D_MODEL * 4);
    prm.ipwB  = (ushort*)alloc((size_t)DEPTH * 2 * D_INNER * D_MODEL * 2);
    prm.xpwB  = (ushort*)alloc((size_t)DEPTH * 48 * D_INNER * 2);
    prm.opwB  = (ushort*)alloc((size_t)DEPTH * D_MODEL * D_INNER * 2);

    // zero the barrier counters (stream-ordered, graph-capturable)
    hipMemsetAsync(prm.bar, 0, 2 * sizeof(int), stream);

    mamba_fused<<<NBLK, 256, 0, stream>>>(prm);
}

// Round 9
// 323.929 us; speedup vs baseline: 5.6729x; 5.6729x over previous
//
#include <hip/hip_runtime.h>
#include <hip/hip_bf16.h>
#include <math.h>

// Problem constants
#define D_MODEL 256
#define DEPTH 2
#define D_INNER 512
#define D_STATE 16
#define D_CONV 4
#define DT_RANK 16
#define BATCH 2
#define SEQLEN 2048
#define MROWS (BATCH * SEQLEN)   // 4096

#define CCH 128   // chunks per batch-sequence
#define LCH 16    // rows per chunk

typedef __attribute__((ext_vector_type(8))) short bf16x8;
typedef __attribute__((ext_vector_type(4))) float f32x4;

__device__ __forceinline__ float silu(float v) {
    return v / (1.0f + __expf(-v));
}

__device__ __forceinline__ ushort f2bf(float f) {
    union { float f; unsigned u; } v; v.f = f;
    unsigned r = v.u + 0x7FFFu + ((v.u >> 16) & 1u);
    return (ushort)(r >> 16);
}

__device__ __forceinline__ float bf2f(ushort u) {
    union { unsigned u; float f; } v; v.u = ((unsigned)u) << 16;
    return v.f;
}

#define XS_STR 260   // f32 stride for 16x256 LN tile (pad vs 32 banks)
#define HS_STR 264   // ushort stride for 16x256 bf16 tile (16B aligned rows)

// ---------------------------------------------------------------------------
// k_cvt: all three weight tensors f32 -> bf16 in one dispatch (grid 512x256).
// ---------------------------------------------------------------------------
__global__ __launch_bounds__(256) void k_cvt(
    const float* __restrict__ ipw, const float* __restrict__ xpw,
    const float* __restrict__ opw, ushort* __restrict__ ipwB,
    ushort* __restrict__ xpwB, ushort* __restrict__ opwB)
{
    size_t tid = (size_t)blockIdx.x * 256 + threadIdx.x;
    {   // ipw: 2*1024*256 elems = 131072 float4 (== grid threads)
        float4 v = ((const float4*)ipw)[tid];
        ushort4 o = { f2bf(v.x), f2bf(v.y), f2bf(v.z), f2bf(v.w) };
        ((ushort4*)ipwB)[tid] = o;
    }
    if (tid < 12288) {   // xpw: 2*48*512/4
        float4 v = ((const float4*)xpw)[tid];
        ushort4 o = { f2bf(v.x), f2bf(v.y), f2bf(v.z), f2bf(v.w) };
        ((ushort4*)xpwB)[tid] = o;
    }
    if (tid < 65536) {   // opw: 2*256*512/4
        float4 v = ((const float4*)opw)[tid];
        ushort4 o = { f2bf(v.x), f2bf(v.y), f2bf(v.z), f2bf(v.w) };
        ((ushort4*)opwB)[tid] = o;
    }
}

// ---------------------------------------------------------------------------
// k_ln_inproj: LayerNorm (block-local, 16 rows) + in_proj MFMA.
// Grid 512: mt = bid>>1 (row tile), nh = bid&1 (n half). Writes xz f32.
// ---------------------------------------------------------------------------
__global__ __launch_bounds__(256) void k_ln_inproj(
    const float* __restrict__ xin, const float* __restrict__ lnwL,
    const float* __restrict__ lnbL, const ushort* __restrict__ ipwL,
    float* __restrict__ xz)
{
    const int t = threadIdx.x, bid = blockIdx.x;
    const int lane = t & 63, w = t >> 6, l15 = lane & 15, quad = lane >> 4;
    __shared__ float  xs[16 * XS_STR];
    __shared__ ushort hs[16 * HS_STR];

    int mt = bid >> 1, nh = bid & 1;
    int m0 = mt * 16;
    #pragma unroll
    for (int i = 0; i < 4; i++) {
        int idx = t + 256 * i;
        int r = idx >> 6, c = (idx & 63) * 4;
        float4 v = *(const float4*)(xin + (size_t)(m0 + r) * D_MODEL + c);
        *(float4*)&xs[r * XS_STR + c] = v;
    }
    __syncthreads();
    int r = t >> 4, ci = t & 15;
    float s = 0.f, sq = 0.f;
    #pragma unroll
    for (int k = 0; k < 16; k++) {
        float v = xs[r * XS_STR + ci + 16 * k];
        s += v; sq += v * v;
    }
    #pragma unroll
    for (int off = 1; off < 16; off <<= 1) {
        s  += __shfl_xor(s, off, 16);
        sq += __shfl_xor(sq, off, 16);
    }
    float mu  = s * (1.0f / 256.f);
    float var = sq * (1.0f / 256.f) - mu * mu;
    float rst = rsqrtf(var + 1e-5f);
    #pragma unroll
    for (int k = 0; k < 16; k++) {
        int c = ci + 16 * k;
        float v = (xs[r * XS_STR + c] - mu) * rst * lnwL[c] + lnbL[c];
        hs[r * HS_STR + c] = f2bf(v);
    }
    __syncthreads();
    int nbase = nh * 512 + w * 128;
    f32x4 acc[8];
    #pragma unroll
    for (int f = 0; f < 8; f++) acc[f] = (f32x4){0.f,0.f,0.f,0.f};
    for (int k0 = 0; k0 < D_MODEL; k0 += 32) {
        bf16x8 af = *(const bf16x8*)&hs[l15 * HS_STR + quad * 8 + k0];
        #pragma unroll
        for (int f = 0; f < 8; f++) {
            const ushort* bp = ipwL + (size_t)(nbase + f * 16 + l15) * D_MODEL + quad * 8 + k0;
            bf16x8 bw = *(const bf16x8*)bp;
            acc[f] = __builtin_amdgcn_mfma_f32_16x16x32_bf16(af, bw, acc[f], 0, 0, 0);
        }
    }
    #pragma unroll
    for (int f = 0; f < 8; f++) {
        int n = nbase + f * 16 + l15;
        #pragma unroll
        for (int r2 = 0; r2 < 4; r2++)
            xz[(size_t)(m0 + quad * 4 + r2) * (2 * D_INNER) + n] = acc[f][r2];
    }
}

// ---------------------------------------------------------------------------
// k_conv: causal depthwise conv(4) + bias + SiLU -> xcB bf16. Grid 512.
// ---------------------------------------------------------------------------
__global__ __launch_bounds__(256) void k_conv(
    const float* __restrict__ xz, const float* __restrict__ cwL,
    const float* __restrict__ cbL, ushort* __restrict__ xcB)
{
    const int t = threadIdx.x, bid = blockIdx.x;
    const int lane = t & 63, w = t >> 6;
    int r0 = bid * 8 + w * 2;
    #pragma unroll
    for (int rr = 0; rr < 2; rr++) {
        int row = r0 + rr;
        int l = row & (SEQLEN - 1);
        #pragma unroll
        for (int dd = 0; dd < 8; dd++) {
            int d = dd * 64 + lane;
            const float* xp = xz + (size_t)row * (2 * D_INNER) + d;
            float s = cbL[d];
            if (l >= 3) s = fmaf(cwL[d * 4 + 0], xp[-3 * 2 * D_INNER], s);
            if (l >= 2) s = fmaf(cwL[d * 4 + 1], xp[-2 * 2 * D_INNER], s);
            if (l >= 1) s = fmaf(cwL[d * 4 + 2], xp[-1 * 2 * D_INNER], s);
            s = fmaf(cwL[d * 4 + 3], xp[0], s);
            xcB[(size_t)row * D_INNER + d] = f2bf(silu(s));
        }
    }
}

// ---------------------------------------------------------------------------
// k_xproj: x_proj MFMA, 768 wave-tiles over 192 blocks.
// ---------------------------------------------------------------------------
__global__ __launch_bounds__(256) void k_xproj(
    const ushort* __restrict__ xcB, const ushort* __restrict__ xpwL,
    float* __restrict__ dbl)
{
    const int t = threadIdx.x, bid = blockIdx.x;
    const int lane = t & 63, w = t >> 6, l15 = lane & 15, quad = lane >> 4;
    int gw = bid * 4 + w;
    int mt = gw / 3, nt = gw - mt * 3;
    int m0 = mt * 16;
    f32x4 acc = (f32x4){0.f,0.f,0.f,0.f};
    for (int k0 = 0; k0 < D_INNER; k0 += 32) {
        bf16x8 af = *(const bf16x8*)(xcB + (size_t)(m0 + l15) * D_INNER + quad * 8 + k0);
        bf16x8 bw = *(const bf16x8*)(xpwL + (size_t)(nt * 16 + l15) * D_INNER + quad * 8 + k0);
        acc = __builtin_amdgcn_mfma_f32_16x16x32_bf16(af, bw, acc, 0, 0, 0);
    }
    int n = nt * 16 + l15;
    #pragma unroll
    for (int r2 = 0; r2 < 4; r2++)
        dbl[(size_t)(m0 + quad * 4 + r2) * 48 + n] = acc[r2];
}

// ---------------------------------------------------------------------------
// k_scan_sum: per-(b,d,chunk) partial scan from h=0, delta inline. Grid 512.
// ---------------------------------------------------------------------------
__global__ __launch_bounds__(256) void k_scan_sum(
    const float* __restrict__ dbl, const ushort* __restrict__ xcB,
    const float* __restrict__ dpwL, const float* __restrict__ dpbL,
    const float* __restrict__ alogL, float* __restrict__ Ssum,
    float* __restrict__ sdsum)
{
    const int t = threadIdx.x, bid = blockIdx.x;
    const int lane = t & 63, w = t >> 6;
    int ct = bid & 31, b = (bid >> 5) & 1, dt2 = bid >> 6;
    int d = dt2 * 64 + lane;
    int c = ct * 4 + w;
    int row0 = b * SEQLEN + c * LCH;
    float a[16], wdp[16];
    #pragma unroll
    for (int n = 0; n < 16; n++) a[n] = -__expf(alogL[(size_t)d * 16 + n]);
    *(float4*)&wdp[0]  = *(const float4*)(dpwL + (size_t)d * 16 + 0);
    *(float4*)&wdp[4]  = *(const float4*)(dpwL + (size_t)d * 16 + 4);
    *(float4*)&wdp[8]  = *(const float4*)(dpwL + (size_t)d * 16 + 8);
    *(float4*)&wdp[12] = *(const float4*)(dpwL + (size_t)d * 16 + 12);
    float bias = dpbL[d];
    float h[16];
    #pragma unroll
    for (int n = 0; n < 16; n++) h[n] = 0.f;
    float sd = 0.f;
    for (int j = 0; j < LCH; j++) {
        int row = row0 + j;
        const float* dp = dbl + (size_t)row * 48;
        float dtv[16], Bv[16];
        *(float4*)&dtv[0]  = *(const float4*)(dp + 0);
        *(float4*)&dtv[4]  = *(const float4*)(dp + 4);
        *(float4*)&dtv[8]  = *(const float4*)(dp + 8);
        *(float4*)&dtv[12] = *(const float4*)(dp + 12);
        *(float4*)&Bv[0]   = *(const float4*)(dp + 16);
        *(float4*)&Bv[4]   = *(const float4*)(dp + 20);
        *(float4*)&Bv[8]   = *(const float4*)(dp + 24);
        *(float4*)&Bv[12]  = *(const float4*)(dp + 28);
        float dot = bias;
        #pragma unroll
        for (int r2 = 0; r2 < 16; r2++) dot = fmaf(dtv[r2], wdp[r2], dot);
        float dl = (dot > 20.f) ? dot : log1pf(__expf(dot));
        float xv = bf2f(xcB[(size_t)row * D_INNER + d]);
        float u = dl * xv;
        sd += dl;
        #pragma unroll
        for (int n = 0; n < 16; n++)
            h[n] = fmaf(__expf(dl * a[n]), h[n], Bv[n] * u);
    }
    size_t sbase = ((size_t)(b * CCH + c) * 16) * D_INNER + d;
    #pragma unroll
    for (int n = 0; n < 16; n++) Ssum[sbase + (size_t)n * D_INNER] = h[n];
    sdsum[(size_t)(b * CCH + c) * D_INNER + d] = sd;
}

// ---------------------------------------------------------------------------
// k_comb: in-place exclusive prefix over chunk summaries. Grid 64.
// ---------------------------------------------------------------------------
__global__ __launch_bounds__(256) void k_comb(
    const float* __restrict__ alogL, const float* __restrict__ sdsum,
    float* __restrict__ Ssum)
{
    const int t = threadIdx.x, bid = blockIdx.x;
    int dt2 = bid & 1;
    int n   = (bid >> 1) & 15;
    int b   = bid >> 5;
    int d   = dt2 * 256 + t;
    float a = -__expf(alogL[(size_t)d * 16 + n]);
    float hi = 0.f;
    #pragma unroll 4
    for (int c = 0; c < CCH; c++) {
        size_t idx = ((size_t)(b * CCH + c) * 16 + n) * D_INNER + d;
        float s  = Ssum[idx];
        float sd = sdsum[(size_t)(b * CCH + c) * D_INNER + d];
        Ssum[idx] = hi;
        hi = fmaf(__expf(a * sd), hi, s);
    }
}

// ---------------------------------------------------------------------------
// k_emit: rescan from true h_init (delta inline), gated bf16 out. Grid 512.
// ---------------------------------------------------------------------------
__global__ __launch_bounds__(256) void k_emit(
    const float* __restrict__ dbl, const ushort* __restrict__ xcB,
    const float* __restrict__ xz, const float* __restrict__ Ssum,
    const float* __restrict__ dpwL, const float* __restrict__ dpbL,
    const float* __restrict__ alogL, const float* __restrict__ dparL,
    ushort* __restrict__ yyB)
{
    const int t = threadIdx.x, bid = blockIdx.x;
    const int lane = t & 63, w = t >> 6;
    int ct = bid & 31, b = (bid >> 5) & 1, dt2 = bid >> 6;
    int d = dt2 * 64 + lane;
    int c = ct * 4 + w;
    int row0 = b * SEQLEN + c * LCH;
    float a[16], wdp[16];
    #pragma unroll
    for (int n = 0; n < 16; n++) a[n] = -__expf(alogL[(size_t)d * 16 + n]);
    *(float4*)&wdp[0]  = *(const float4*)(dpwL + (size_t)d * 16 + 0);
    *(float4*)&wdp[4]  = *(const float4*)(dpwL + (size_t)d * 16 + 4);
    *(float4*)&wdp[8]  = *(const float4*)(dpwL + (size_t)d * 16 + 8);
    *(float4*)&wdp[12] = *(const float4*)(dpwL + (size_t)d * 16 + 12);
    float bias = dpbL[d];
    float h[16];
    size_t sbase = ((size_t)(b * CCH + c) * 16) * D_INNER + d;
    #pragma unroll
    for (int n = 0; n < 16; n++) h[n] = Ssum[sbase + (size_t)n * D_INNER];
    float Dd = dparL[d];
    for (int j = 0; j < LCH; j++) {
        int row = row0 + j;
        const float* dp = dbl + (size_t)row * 48;
        float dtv[16], Bv[16], Cv[16];
        *(float4*)&dtv[0]  = *(const float4*)(dp + 0);
        *(float4*)&dtv[4]  = *(const float4*)(dp + 4);
        *(float4*)&dtv[8]  = *(const float4*)(dp + 8);
        *(float4*)&dtv[12] = *(const float4*)(dp + 12);
        *(float4*)&Bv[0]   = *(const float4*)(dp + 16);
        *(float4*)&Bv[4]   = *(const float4*)(dp + 20);
        *(float4*)&Bv[8]   = *(const float4*)(dp + 24);
        *(float4*)&Bv[12]  = *(const float4*)(dp + 28);
        *(float4*)&Cv[0]   = *(const float4*)(dp + 32);
        *(float4*)&Cv[4]   = *(const float4*)(dp + 36);
        *(float4*)&Cv[8]   = *(const float4*)(dp + 40);
        *(float4*)&Cv[12]  = *(const float4*)(dp + 44);
        float dot = bias;
        #pragma unroll
        for (int r2 = 0; r2 < 16; r2++) dot = fmaf(dtv[r2], wdp[r2], dot);
        float dl = (dot > 20.f) ? dot : log1pf(__expf(dot));
        float xv = bf2f(xcB[(size_t)row * D_INNER + d]);
        float z  = xz[(size_t)row * (2 * D_INNER) + D_INNER + d];
        float u = dl * xv;
        float y0 = 0.f, y1 = 0.f, y2 = 0.f, y3 = 0.f;
        #pragma unroll
        for (int n = 0; n < 16; n += 4) {
            h[n + 0] = fmaf(__expf(dl * a[n + 0]), h[n + 0], Bv[n + 0] * u);
            h[n + 1] = fmaf(__expf(dl * a[n + 1]), h[n + 1], Bv[n + 1] * u);
            h[n + 2] = fmaf(__expf(dl * a[n + 2]), h[n + 2], Bv[n + 2] * u);
            h[n + 3] = fmaf(__expf(dl * a[n + 3]), h[n + 3], Bv[n + 3] * u);
            y0 = fmaf(h[n + 0], Cv[n + 0], y0);
            y1 = fmaf(h[n + 1], Cv[n + 1], y1);
            y2 = fmaf(h[n + 2], Cv[n + 2], y2);
            y3 = fmaf(h[n + 3], Cv[n + 3], y3);
        }
        float y = (y0 + y1) + (y2 + y3) + xv * Dd;
        yyB[(size_t)row * D_INNER + d] = f2bf(y * silu(z));
    }
}

// ---------------------------------------------------------------------------
// k_outproj: out_proj MFMA + residual. Grid 512.
// ---------------------------------------------------------------------------
__global__ __launch_bounds__(256) void k_outproj(
    const ushort* __restrict__ yyB, const ushort* __restrict__ opwL,
    const float* __restrict__ xin, float* __restrict__ xout)
{
    const int t = threadIdx.x, bid = blockIdx.x;
    const int lane = t & 63, w = t >> 6, l15 = lane & 15, quad = lane >> 4;
    int mt = bid >> 1, nh = bid & 1;
    int m0 = mt * 16;
    int nbase = nh * 128 + w * 32;
    f32x4 acc[2];
    acc[0] = (f32x4){0.f,0.f,0.f,0.f};
    acc[1] = (f32x4){0.f,0.f,0.f,0.f};
    for (int k0 = 0; k0 < D_INNER; k0 += 32) {
        bf16x8 af = *(const bf16x8*)(yyB + (size_t)(m0 + l15) * D_INNER + quad * 8 + k0);
        #pragma unroll
        for (int f = 0; f < 2; f++) {
            const ushort* bp = opwL + (size_t)(nbase + f * 16 + l15) * D_INNER + quad * 8 + k0;
            bf16x8 bw = *(const bf16x8*)bp;
            acc[f] = __builtin_amdgcn_mfma_f32_16x16x32_bf16(af, bw, acc[f], 0, 0, 0);
        }
    }
    #pragma unroll
    for (int f = 0; f < 2; f++) {
        int n = nbase + f * 16 + l15;
        #pragma unroll
        for (int r2 = 0; r2 < 4; r2++) {
            int row = m0 + quad * 4 + r2;
            xout[(size_t)row * D_MODEL + n] =
                acc[f][r2] + xin[(size_t)row * D_MODEL + n];
        }
    }
}

// ---------------------------------------------------------------------------
// Launch
// ---------------------------------------------------------------------------
extern "C" void kernel_launch(void* const* d_in, const int* in_sizes, int n_in,
                              void* d_out, int out_size, void* d_ws, size_t ws_size,
                              hipStream_t stream)
{
    const float* x    = (const float*)d_in[0];
    const float* lnw  = (const float*)d_in[1];
    const float* lnb  = (const float*)d_in[2];
    const float* ipw  = (const float*)d_in[3];
    const float* cw   = (const float*)d_in[4];
    const float* cb   = (const float*)d_in[5];
    const float* xpw  = (const float*)d_in[6];
    const float* dpw  = (const float*)d_in[7];
    const float* dpb  = (const float*)d_in[8];
    const float* alog = (const float*)d_in[9];
    const float* dpar = (const float*)d_in[10];
    const float* opw  = (const float*)d_in[11];
    float* out = (float*)d_out;

    char* p = (char*)d_ws;
    auto alloc = [&](size_t bytes) { char* r = p; p += (bytes + 255) & ~(size_t)255; return r; };
    float*  xz    = (float*)alloc((size_t)MROWS * 2 * D_INNER * 4);
    ushort* xcB   = (ushort*)alloc((size_t)MROWS * D_INNER * 2);
    float*  dbl   = (float*)alloc((size_t)MROWS * 48 * 4);
    float*  Ssum  = (float*)alloc((size_t)BATCH * CCH * 16 * D_INNER * 4);
    float*  sdsum = (float*)alloc((size_t)BATCH * CCH * D_INNER * 4);
    ushort* yyB   = (ushort*)alloc((size_t)MROWS * D_INNER * 2);
    float*  xbuf  = (float*)alloc((size_t)MROWS * D_MODEL * 4);
    ushort* ipwB  = (ushort*)alloc((size_t)DEPTH * 2 * D_INNER * D_MODEL * 2);
    ushort* xpwB  = (ushort*)alloc((size_t)DEPTH * 48 * D_INNER * 2);
    ushort* opwB  = (ushort*)alloc((size_t)DEPTH * D_MODEL * D_INNER * 2);

    k_cvt<<<512, 256, 0, stream>>>(ipw, xpw, opw, ipwB, xpwB, opwB);

    for (int lyr = 0; lyr < DEPTH; lyr++) {
        const float* xin = (lyr == 0) ? x : xbuf;
        float* xout = (lyr == DEPTH - 1) ? out : xbuf;

        k_ln_inproj<<<512, 256, 0, stream>>>(
            xin, lnw + lyr * D_MODEL, lnb + lyr * D_MODEL,
            ipwB + (size_t)lyr * 2 * D_INNER * D_MODEL, xz);

        k_conv<<<512, 256, 0, stream>>>(
            xz, cw + (size_t)lyr * D_INNER * D_CONV, cb + lyr * D_INNER, xcB);

        k_xproj<<<192, 256, 0, stream>>>(
            xcB, xpwB + (size_t)lyr * 48 * D_INNER, dbl);

        k_scan_sum<<<512, 256, 0, stream>>>(
            dbl, xcB, dpw + (size_t)lyr * D_INNER * DT_RANK, dpb + lyr * D_INNER,
            alog + (size_t)lyr * D_INNER * D_STATE, Ssum, sdsum);

        k_comb<<<64, 256, 0, stream>>>(
            alog + (size_t)lyr * D_INNER * D_STATE, sdsum, Ssum);

        k_emit<<<512, 256, 0, stream>>>(
            dbl, xcB, xz, Ssum,
            dpw + (size_t)lyr * D_INNER * DT_RANK, dpb + lyr * D_INNER,
            alog + (size_t)lyr * D_INNER * D_STATE, dpar + lyr * D_INNER, yyB);

        k_outproj<<<512, 256, 0, stream>>>(
            yyB, opwB + (size_t)lyr * D_MODEL * D_INNER, xin, xout);
    }
}

// Round 10
// 279.610 us; speedup vs baseline: 6.5721x; 1.1585x over previous
//
#include <hip/hip_runtime.h>
#include <hip/hip_bf16.h>
#include <math.h>

// Problem constants
#define D_MODEL 256
#define DEPTH 2
#define D_INNER 512
#define D_STATE 16
#define D_CONV 4
#define DT_RANK 16
#define BATCH 2
#define SEQLEN 2048
#define MROWS (BATCH * SEQLEN)   // 4096

#define CCH 128   // chunks per batch-sequence
#define LCH 16    // rows per chunk

typedef __attribute__((ext_vector_type(8))) short bf16x8;
typedef __attribute__((ext_vector_type(4))) float f32x4;

__device__ __forceinline__ float silu(float v) {
    return v / (1.0f + __expf(-v));
}

__device__ __forceinline__ ushort f2bf(float f) {
    union { float f; unsigned u; } v; v.f = f;
    unsigned r = v.u + 0x7FFFu + ((v.u >> 16) & 1u);
    return (ushort)(r >> 16);
}

__device__ __forceinline__ float bf2f(ushort u) {
    union { unsigned u; float f; } v; v.u = ((unsigned)u) << 16;
    return v.f;
}

#define XS_STR 260   // f32 stride for 16x256 LN tile
#define HS_STR 264   // ushort stride for 16x256 bf16 tile
#define XC_STR 520   // ushort stride for xc LDS tile (2-way max conflicts)

// ---------------------------------------------------------------------------
// k_cvt: all three weight tensors f32 -> bf16 in one dispatch (grid 512x256).
// ---------------------------------------------------------------------------
__global__ __launch_bounds__(256) void k_cvt(
    const float* __restrict__ ipw, const float* __restrict__ xpw,
    const float* __restrict__ opw, ushort* __restrict__ ipwB,
    ushort* __restrict__ xpwB, ushort* __restrict__ opwB)
{
    size_t tid = (size_t)blockIdx.x * 256 + threadIdx.x;
    {
        float4 v = ((const float4*)ipw)[tid];
        ushort4 o = { f2bf(v.x), f2bf(v.y), f2bf(v.z), f2bf(v.w) };
        ((ushort4*)ipwB)[tid] = o;
    }
    if (tid < 12288) {
        float4 v = ((const float4*)xpw)[tid];
        ushort4 o = { f2bf(v.x), f2bf(v.y), f2bf(v.z), f2bf(v.w) };
        ((ushort4*)xpwB)[tid] = o;
    }
    if (tid < 65536) {
        float4 v = ((const float4*)opw)[tid];
        ushort4 o = { f2bf(v.x), f2bf(v.y), f2bf(v.z), f2bf(v.w) };
        ((ushort4*)opwB)[tid] = o;
    }
}

// ---------------------------------------------------------------------------
// k_ln_inproj: LayerNorm + in_proj MFMA. Grid 1024: mt=bid>>2, nq=bid&3.
// n-quarter 0,1 -> xiB bf16; 2,3 -> zsB = silu(z) bf16.
// ---------------------------------------------------------------------------
__global__ __launch_bounds__(256) void k_ln_inproj(
    const float* __restrict__ xin, const float* __restrict__ lnwL,
    const float* __restrict__ lnbL, const ushort* __restrict__ ipwL,
    ushort* __restrict__ xiB, ushort* __restrict__ zsB)
{
    const int t = threadIdx.x, bid = blockIdx.x;
    const int lane = t & 63, w = t >> 6, l15 = lane & 15, quad = lane >> 4;
    __shared__ float  xs[16 * XS_STR];
    __shared__ ushort hs[16 * HS_STR];

    int mt = bid >> 2, nq = bid & 3;
    int m0 = mt * 16;
    #pragma unroll
    for (int i = 0; i < 4; i++) {
        int idx = t + 256 * i;
        int r = idx >> 6, c = (idx & 63) * 4;
        float4 v = *(const float4*)(xin + (size_t)(m0 + r) * D_MODEL + c);
        *(float4*)&xs[r * XS_STR + c] = v;
    }
    __syncthreads();
    int r = t >> 4, ci = t & 15;
    float s = 0.f, sq = 0.f;
    #pragma unroll
    for (int k = 0; k < 16; k++) {
        float v = xs[r * XS_STR + ci + 16 * k];
        s += v; sq += v * v;
    }
    #pragma unroll
    for (int off = 1; off < 16; off <<= 1) {
        s  += __shfl_xor(s, off, 16);
        sq += __shfl_xor(sq, off, 16);
    }
    float mu  = s * (1.0f / 256.f);
    float var = sq * (1.0f / 256.f) - mu * mu;
    float rst = rsqrtf(var + 1e-5f);
    #pragma unroll
    for (int k = 0; k < 16; k++) {
        int c = ci + 16 * k;
        float v = (xs[r * XS_STR + c] - mu) * rst * lnwL[c] + lnbL[c];
        hs[r * HS_STR + c] = f2bf(v);
    }
    __syncthreads();
    int nbase = nq * 256 + w * 64;
    f32x4 acc[4];
    #pragma unroll
    for (int f = 0; f < 4; f++) acc[f] = (f32x4){0.f,0.f,0.f,0.f};
    for (int k0 = 0; k0 < D_MODEL; k0 += 32) {
        bf16x8 af = *(const bf16x8*)&hs[l15 * HS_STR + quad * 8 + k0];
        #pragma unroll
        for (int f = 0; f < 4; f++) {
            const ushort* bp = ipwL + (size_t)(nbase + f * 16 + l15) * D_MODEL + quad * 8 + k0;
            bf16x8 bw = *(const bf16x8*)bp;
            acc[f] = __builtin_amdgcn_mfma_f32_16x16x32_bf16(af, bw, acc[f], 0, 0, 0);
        }
    }
    #pragma unroll
    for (int f = 0; f < 4; f++) {
        int n = nbase + f * 16 + l15;
        #pragma unroll
        for (int r2 = 0; r2 < 4; r2++) {
            int row = m0 + quad * 4 + r2;
            float v = acc[f][r2];
            if (nq < 2) xiB[(size_t)row * D_INNER + n] = f2bf(v);
            else        zsB[(size_t)row * D_INNER + (n - 512)] = f2bf(silu(v));
        }
    }
}

// ---------------------------------------------------------------------------
// k_convxp: conv(4)+SiLU + x_proj MFMA + scan_sum, fused per 16-row chunk.
// Grid 256 blocks (== chunk id), 512 threads.
// ---------------------------------------------------------------------------
__global__ __launch_bounds__(512) void k_convxp(
    const ushort* __restrict__ xiB, const float* __restrict__ cwL,
    const float* __restrict__ cbL, const ushort* __restrict__ xpwL,
    const float* __restrict__ dpwL, const float* __restrict__ dpbL,
    const float* __restrict__ alogL, ushort* __restrict__ xcB,
    float* __restrict__ dbl, float* __restrict__ Ssum,
    float* __restrict__ sdsum)
{
    const int t = threadIdx.x, bid = blockIdx.x;
    const int lane = t & 63, w = t >> 6, l15 = lane & 15, quad = lane >> 4;
    __shared__ ushort xi_s[19 * 512];
    __shared__ ushort xc_s[16 * XC_STR];
    __shared__ float  dbl_s[16 * 52];
    int m0 = bid * 16;                 // global row base; chunk id == bid

    // ---- Phase 1: stage xi rows m0-3 .. m0+15 (bf16) ----
    for (int i = t; i < 19 * 64; i += 512) {
        int rr = i >> 6, o8 = i & 63;
        int grow = m0 - 3 + rr;
        uint4 v = (uint4){0u, 0u, 0u, 0u};
        if (grow >= 0)
            v = *(const uint4*)(xiB + (size_t)grow * D_INNER + o8 * 8);
        *(uint4*)&xi_s[rr * 512 + o8 * 8] = v;
    }
    __syncthreads();

    // ---- Phase 2: conv + SiLU -> xc_s (LDS) + xcB (global) ----
    float cw0 = cwL[t * 4 + 0], cw1 = cwL[t * 4 + 1];
    float cw2 = cwL[t * 4 + 2], cw3 = cwL[t * 4 + 3];
    float cbv = cbL[t];
    #pragma unroll
    for (int rl = 0; rl < 16; rl++) {
        int grow = m0 + rl;
        int l = grow & (SEQLEN - 1);
        float s = cbv;
        if (l >= 3) s = fmaf(cw0, bf2f(xi_s[(rl + 0) * 512 + t]), s);
        if (l >= 2) s = fmaf(cw1, bf2f(xi_s[(rl + 1) * 512 + t]), s);
        if (l >= 1) s = fmaf(cw2, bf2f(xi_s[(rl + 2) * 512 + t]), s);
        s = fmaf(cw3, bf2f(xi_s[(rl + 3) * 512 + t]), s);
        ushort xcv = f2bf(silu(s));
        xc_s[rl * XC_STR + t] = xcv;
        xcB[(size_t)grow * D_INNER + t] = xcv;
    }
    __syncthreads();

    // ---- Phase 3: x_proj MFMA (waves 0..2, one 16-n tile each) ----
    if (w < 3) {
        int nt = w;
        f32x4 acc = (f32x4){0.f, 0.f, 0.f, 0.f};
        for (int k0 = 0; k0 < D_INNER; k0 += 32) {
            bf16x8 af = *(const bf16x8*)&xc_s[l15 * XC_STR + quad * 8 + k0];
            bf16x8 bw = *(const bf16x8*)(xpwL + (size_t)(nt * 16 + l15) * D_INNER + quad * 8 + k0);
            acc = __builtin_amdgcn_mfma_f32_16x16x32_bf16(af, bw, acc, 0, 0, 0);
        }
        int n = nt * 16 + l15;
        #pragma unroll
        for (int r2 = 0; r2 < 4; r2++) {
            int rl = quad * 4 + r2;
            dbl_s[rl * 52 + n] = acc[r2];
            dbl[(size_t)(m0 + rl) * 48 + n] = acc[r2];
        }
    }
    __syncthreads();

    // ---- Phase 4: scan_sum (d = t), delta inline from dbl_s ----
    float a[16], wdp[16];
    #pragma unroll
    for (int n = 0; n < 16; n++) a[n] = -__expf(alogL[(size_t)t * 16 + n]);
    *(float4*)&wdp[0]  = *(const float4*)(dpwL + (size_t)t * 16 + 0);
    *(float4*)&wdp[4]  = *(const float4*)(dpwL + (size_t)t * 16 + 4);
    *(float4*)&wdp[8]  = *(const float4*)(dpwL + (size_t)t * 16 + 8);
    *(float4*)&wdp[12] = *(const float4*)(dpwL + (size_t)t * 16 + 12);
    float bias = dpbL[t];
    float h[16];
    #pragma unroll
    for (int n = 0; n < 16; n++) h[n] = 0.f;
    float sd = 0.f;
    for (int j = 0; j < LCH; j++) {
        const float* dp = &dbl_s[j * 52];
        float dot = bias;
        #pragma unroll
        for (int r2 = 0; r2 < 16; r2++) dot = fmaf(dp[r2], wdp[r2], dot);
        float dl = (dot > 20.f) ? dot : log1pf(__expf(dot));
        float xv = bf2f(xc_s[j * XC_STR + t]);
        float u = dl * xv;
        sd += dl;
        #pragma unroll
        for (int n = 0; n < 16; n++)
            h[n] = fmaf(__expf(dl * a[n]), h[n], dp[16 + n] * u);
    }
    size_t sbase = ((size_t)bid * 16) * D_INNER + t;
    #pragma unroll
    for (int n = 0; n < 16; n++) Ssum[sbase + (size_t)n * D_INNER] = h[n];
    sdsum[(size_t)bid * D_INNER + t] = sd;
}

// ---------------------------------------------------------------------------
// k_comb: in-place exclusive prefix over chunk summaries. Grid 64.
// ---------------------------------------------------------------------------
__global__ __launch_bounds__(256) void k_comb(
    const float* __restrict__ alogL, const float* __restrict__ sdsum,
    float* __restrict__ Ssum)
{
    const int t = threadIdx.x, bid = blockIdx.x;
    int dt2 = bid & 1;
    int n   = (bid >> 1) & 15;
    int b   = bid >> 5;
    int d   = dt2 * 256 + t;
    float a = -__expf(alogL[(size_t)d * 16 + n]);
    float hi = 0.f;
    #pragma unroll 4
    for (int c = 0; c < CCH; c++) {
        size_t idx = ((size_t)(b * CCH + c) * 16 + n) * D_INNER + d;
        float s  = Ssum[idx];
        float sd = sdsum[(size_t)(b * CCH + c) * D_INNER + d];
        Ssum[idx] = hi;
        hi = fmaf(__expf(a * sd), hi, s);
    }
}

// ---------------------------------------------------------------------------
// k_emit: rescan from true h_init (delta inline), gate from zsB. Grid 512.
// ---------------------------------------------------------------------------
__global__ __launch_bounds__(256) void k_emit(
    const float* __restrict__ dbl, const ushort* __restrict__ xcB,
    const ushort* __restrict__ zsB, const float* __restrict__ Ssum,
    const float* __restrict__ dpwL, const float* __restrict__ dpbL,
    const float* __restrict__ alogL, const float* __restrict__ dparL,
    ushort* __restrict__ yyB)
{
    const int t = threadIdx.x, bid = blockIdx.x;
    const int lane = t & 63, w = t >> 6;
    int ct = bid & 31, b = (bid >> 5) & 1, dt2 = bid >> 6;
    int d = dt2 * 64 + lane;
    int c = ct * 4 + w;
    int row0 = b * SEQLEN + c * LCH;
    float a[16], wdp[16];
    #pragma unroll
    for (int n = 0; n < 16; n++) a[n] = -__expf(alogL[(size_t)d * 16 + n]);
    *(float4*)&wdp[0]  = *(const float4*)(dpwL + (size_t)d * 16 + 0);
    *(float4*)&wdp[4]  = *(const float4*)(dpwL + (size_t)d * 16 + 4);
    *(float4*)&wdp[8]  = *(const float4*)(dpwL + (size_t)d * 16 + 8);
    *(float4*)&wdp[12] = *(const float4*)(dpwL + (size_t)d * 16 + 12);
    float bias = dpbL[d];
    float h[16];
    size_t sbase = ((size_t)(b * CCH + c) * 16) * D_INNER + d;
    #pragma unroll
    for (int n = 0; n < 16; n++) h[n] = Ssum[sbase + (size_t)n * D_INNER];
    float Dd = dparL[d];
    for (int j = 0; j < LCH; j++) {
        int row = row0 + j;
        const float* dp = dbl + (size_t)row * 48;
        float dtv[16], Bv[16], Cv[16];
        *(float4*)&dtv[0]  = *(const float4*)(dp + 0);
        *(float4*)&dtv[4]  = *(const float4*)(dp + 4);
        *(float4*)&dtv[8]  = *(const float4*)(dp + 8);
        *(float4*)&dtv[12] = *(const float4*)(dp + 12);
        *(float4*)&Bv[0]   = *(const float4*)(dp + 16);
        *(float4*)&Bv[4]   = *(const float4*)(dp + 20);
        *(float4*)&Bv[8]   = *(const float4*)(dp + 24);
        *(float4*)&Bv[12]  = *(const float4*)(dp + 28);
        *(float4*)&Cv[0]   = *(const float4*)(dp + 32);
        *(float4*)&Cv[4]   = *(const float4*)(dp + 36);
        *(float4*)&Cv[8]   = *(const float4*)(dp + 40);
        *(float4*)&Cv[12]  = *(const float4*)(dp + 44);
        float dot = bias;
        #pragma unroll
        for (int r2 = 0; r2 < 16; r2++) dot = fmaf(dtv[r2], wdp[r2], dot);
        float dl = (dot > 20.f) ? dot : log1pf(__expf(dot));
        float xv = bf2f(xcB[(size_t)row * D_INNER + d]);
        float gate = bf2f(zsB[(size_t)row * D_INNER + d]);
        float u = dl * xv;
        float y0 = 0.f, y1 = 0.f, y2 = 0.f, y3 = 0.f;
        #pragma unroll
        for (int n = 0; n < 16; n += 4) {
            h[n + 0] = fmaf(__expf(dl * a[n + 0]), h[n + 0], Bv[n + 0] * u);
            h[n + 1] = fmaf(__expf(dl * a[n + 1]), h[n + 1], Bv[n + 1] * u);
            h[n + 2] = fmaf(__expf(dl * a[n + 2]), h[n + 2], Bv[n + 2] * u);
            h[n + 3] = fmaf(__expf(dl * a[n + 3]), h[n + 3], Bv[n + 3] * u);
            y0 = fmaf(h[n + 0], Cv[n + 0], y0);
            y1 = fmaf(h[n + 1], Cv[n + 1], y1);
            y2 = fmaf(h[n + 2], Cv[n + 2], y2);
            y3 = fmaf(h[n + 3], Cv[n + 3], y3);
        }
        float y = (y0 + y1) + (y2 + y3) + xv * Dd;
        yyB[(size_t)row * D_INNER + d] = f2bf(y * gate);
    }
}

// ---------------------------------------------------------------------------
// k_outproj: out_proj MFMA + residual. Grid 1024: mt=bid>>2, nq=bid&3.
// ---------------------------------------------------------------------------
__global__ __launch_bounds__(256) void k_outproj(
    const ushort* __restrict__ yyB, const ushort* __restrict__ opwL,
    const float* __restrict__ xin, float* __restrict__ xout)
{
    const int t = threadIdx.x, bid = blockIdx.x;
    const int lane = t & 63, w = t >> 6, l15 = lane & 15, quad = lane >> 4;
    int mt = bid >> 2, nq = bid & 3;
    int m0 = mt * 16;
    int n = nq * 64 + w * 16 + l15;
    f32x4 acc = (f32x4){0.f, 0.f, 0.f, 0.f};
    for (int k0 = 0; k0 < D_INNER; k0 += 32) {
        bf16x8 af = *(const bf16x8*)(yyB + (size_t)(m0 + l15) * D_INNER + quad * 8 + k0);
        bf16x8 bw = *(const bf16x8*)(opwL + (size_t)n * D_INNER + quad * 8 + k0);
        acc = __builtin_amdgcn_mfma_f32_16x16x32_bf16(af, bw, acc, 0, 0, 0);
    }
    #pragma unroll
    for (int r2 = 0; r2 < 4; r2++) {
        int row = m0 + quad * 4 + r2;
        xout[(size_t)row * D_MODEL + n] =
            acc[r2] + xin[(size_t)row * D_MODEL + n];
    }
}

// ---------------------------------------------------------------------------
// Launch
// ---------------------------------------------------------------------------
extern "C" void kernel_launch(void* const* d_in, const int* in_sizes, int n_in,
                              void* d_out, int out_size, void* d_ws, size_t ws_size,
                              hipStream_t stream)
{
    const float* x    = (const float*)d_in[0];
    const float* lnw  = (const float*)d_in[1];
    const float* lnb  = (const float*)d_in[2];
    const float* ipw  = (const float*)d_in[3];
    const float* cw   = (const float*)d_in[4];
    const float* cb   = (const float*)d_in[5];
    const float* xpw  = (const float*)d_in[6];
    const float* dpw  = (const float*)d_in[7];
    const float* dpb  = (const float*)d_in[8];
    const float* alog = (const float*)d_in[9];
    const float* dpar = (const float*)d_in[10];
    const float* opw  = (const float*)d_in[11];
    float* out = (float*)d_out;

    char* p = (char*)d_ws;
    auto alloc = [&](size_t bytes) { char* r = p; p += (bytes + 255) & ~(size_t)255; return r; };
    ushort* xiB   = (ushort*)alloc((size_t)MROWS * D_INNER * 2);
    ushort* zsB   = (ushort*)alloc((size_t)MROWS * D_INNER * 2);
    ushort* xcB   = (ushort*)alloc((size_t)MROWS * D_INNER * 2);
    float*  dbl   = (float*)alloc((size_t)MROWS * 48 * 4);
    float*  Ssum  = (float*)alloc((size_t)BATCH * CCH * 16 * D_INNER * 4);
    float*  sdsum = (float*)alloc((size_t)BATCH * CCH * D_INNER * 4);
    ushort* yyB   = (ushort*)alloc((size_t)MROWS * D_INNER * 2);
    float*  xbuf  = (float*)alloc((size_t)MROWS * D_MODEL * 4);
    ushort* ipwB  = (ushort*)alloc((size_t)DEPTH * 2 * D_INNER * D_MODEL * 2);
    ushort* xpwB  = (ushort*)alloc((size_t)DEPTH * 48 * D_INNER * 2);
    ushort* opwB  = (ushort*)alloc((size_t)DEPTH * D_MODEL * D_INNER * 2);

    k_cvt<<<512, 256, 0, stream>>>(ipw, xpw, opw, ipwB, xpwB, opwB);

    for (int lyr = 0; lyr < DEPTH; lyr++) {
        const float* xin = (lyr == 0) ? x : xbuf;
        float* xout = (lyr == DEPTH - 1) ? out : xbuf;
        const float* alogL = alog + (size_t)lyr * D_INNER * D_STATE;
        const float* dpwL  = dpw + (size_t)lyr * D_INNER * DT_RANK;
        const float* dpbL  = dpb + lyr * D_INNER;

        k_ln_inproj<<<1024, 256, 0, stream>>>(
            xin, lnw + lyr * D_MODEL, lnb + lyr * D_MODEL,
            ipwB + (size_t)lyr * 2 * D_INNER * D_MODEL, xiB, zsB);

        k_convxp<<<256, 512, 0, stream>>>(
            xiB, cw + (size_t)lyr * D_INNER * D_CONV, cb + lyr * D_INNER,
            xpwB + (size_t)lyr * 48 * D_INNER, dpwL, dpbL, alogL,
            xcB, dbl, Ssum, sdsum);

        k_comb<<<64, 256, 0, stream>>>(alogL, sdsum, Ssum);

        k_emit<<<512, 256, 0, stream>>>(
            dbl, xcB, zsB, Ssum, dpwL, dpbL, alogL,
            dpar + lyr * D_INNER, yyB);

        k_outproj<<<1024, 256, 0, stream>>>(
            yyB, opwB + (size_t)lyr * D_MODEL * D_INNER, xin, xout);
    }
}

// Round 11
// 261.368 us; speedup vs baseline: 7.0308x; 1.0698x over previous
//
#include <hip/hip_runtime.h>
#include <hip/hip_bf16.h>
#include <math.h>

// Problem constants
#define D_MODEL 256
#define DEPTH 2
#define D_INNER 512
#define D_STATE 16
#define D_CONV 4
#define DT_RANK 16
#define BATCH 2
#define SEQLEN 2048
#define MROWS (BATCH * SEQLEN)   // 4096

#define CCH 128   // chunks per batch-sequence
#define LCH 16    // rows per chunk

typedef __attribute__((ext_vector_type(8))) short bf16x8;
typedef __attribute__((ext_vector_type(4))) float f32x4;

__device__ __forceinline__ float silu(float v) {
    return v / (1.0f + __expf(-v));
}

__device__ __forceinline__ ushort f2bf(float f) {
    union { float f; unsigned u; } v; v.f = f;
    unsigned r = v.u + 0x7FFFu + ((v.u >> 16) & 1u);
    return (ushort)(r >> 16);
}

__device__ __forceinline__ float bf2f(ushort u) {
    union { unsigned u; float f; } v; v.u = ((unsigned)u) << 16;
    return v.f;
}

#define XS_STR 260   // f32 stride, 19-row LN tile
#define HS_STR 264   // ushort stride, 19-row bf16 LN output
#define XC_STR 520   // ushort stride, xc/yy LDS tiles (2-way conflicts max)

// ---------------------------------------------------------------------------
// k_cvt: all three weight tensors f32 -> bf16 in one dispatch (grid 512x256).
// ---------------------------------------------------------------------------
__global__ __launch_bounds__(256) void k_cvt(
    const float* __restrict__ ipw, const float* __restrict__ xpw,
    const float* __restrict__ opw, ushort* __restrict__ ipwB,
    ushort* __restrict__ xpwB, ushort* __restrict__ opwB)
{
    size_t tid = (size_t)blockIdx.x * 256 + threadIdx.x;
    {
        float4 v = ((const float4*)ipw)[tid];
        ushort4 o = { f2bf(v.x), f2bf(v.y), f2bf(v.z), f2bf(v.w) };
        ((ushort4*)ipwB)[tid] = o;
    }
    if (tid < 12288) {
        float4 v = ((const float4*)xpw)[tid];
        ushort4 o = { f2bf(v.x), f2bf(v.y), f2bf(v.z), f2bf(v.w) };
        ((ushort4*)xpwB)[tid] = o;
    }
    if (tid < 65536) {
        float4 v = ((const float4*)opw)[tid];
        ushort4 o = { f2bf(v.x), f2bf(v.y), f2bf(v.z), f2bf(v.w) };
        ((ushort4*)opwB)[tid] = o;
    }
}

// ---------------------------------------------------------------------------
// k_front: LN (19 rows incl. 3-row conv halo) + in_proj MFMA + conv + SiLU
//          + x_proj MFMA + scan_sum, all per 16-row chunk. Grid 256 x 512.
// Halo xi is recomputed in-block (tile0), so xi never hits global memory.
// ---------------------------------------------------------------------------
__global__ __launch_bounds__(512) void k_front(
    const float* __restrict__ xin, const float* __restrict__ lnwL,
    const float* __restrict__ lnbL, const ushort* __restrict__ ipwL,
    const float* __restrict__ cwL, const float* __restrict__ cbL,
    const ushort* __restrict__ xpwL, const float* __restrict__ dpwL,
    const float* __restrict__ dpbL, const float* __restrict__ alogL,
    ushort* __restrict__ zsB, ushort* __restrict__ xcB,
    float* __restrict__ dbl, float* __restrict__ Ssum,
    float* __restrict__ sdsum)
{
    const int t = threadIdx.x, bid = blockIdx.x;
    const int lane = t & 63, w = t >> 6, l15 = lane & 15, quad = lane >> 4;
    __shared__ float  xs[19 * XS_STR];     // 19.8 KB
    __shared__ ushort hs[19 * HS_STR];     // 10.0 KB
    __shared__ ushort xi_s[19 * 512];      // 19.5 KB  rows: m0-3 .. m0+15
    __shared__ ushort xc_s[16 * XC_STR];   // 16.6 KB
    __shared__ float  dbl_s[16 * 52];      //  3.3 KB
    int m0 = bid * 16;

    // ---- stage x rows m0-3 .. m0+15 (clamp row<0; batch masking via conv) --
    for (int i = t; i < 19 * 64; i += 512) {
        int r = i >> 6, c = (i & 63) * 4;
        int grow = m0 - 3 + r; if (grow < 0) grow = 0;
        float4 v = *(const float4*)(xin + (size_t)grow * D_MODEL + c);
        *(float4*)&xs[r * XS_STR + c] = v;
    }
    __syncthreads();

    // ---- LayerNorm, 19 rows x 16 threads ----
    if (t < 19 * 16) {
        int r = t >> 4, ci = t & 15;
        float s = 0.f, sq = 0.f;
        #pragma unroll
        for (int k = 0; k < 16; k++) {
            float v = xs[r * XS_STR + ci + 16 * k];
            s += v; sq += v * v;
        }
        #pragma unroll
        for (int off = 1; off < 16; off <<= 1) {
            s  += __shfl_xor(s, off, 16);
            sq += __shfl_xor(sq, off, 16);
        }
        float mu  = s * (1.0f / 256.f);
        float var = sq * (1.0f / 256.f) - mu * mu;
        float rst = rsqrtf(var + 1e-5f);
        #pragma unroll
        for (int k = 0; k < 16; k++) {
            int c = ci + 16 * k;
            float v = (xs[r * XS_STR + c] - mu) * rst * lnwL[c] + lnbL[c];
            hs[r * HS_STR + c] = f2bf(v);
        }
    }
    __syncthreads();

    // ---- in_proj MFMA tile0: rows m0-3..m0+12, keep halo rows 0..2, n<512 --
    #pragma unroll
    for (int f = 0; f < 4; f++) {
        int n0 = w * 64 + f * 16;
        f32x4 acc = (f32x4){0.f, 0.f, 0.f, 0.f};
        for (int k0 = 0; k0 < D_MODEL; k0 += 32) {
            bf16x8 af = *(const bf16x8*)&hs[l15 * HS_STR + quad * 8 + k0];
            bf16x8 bw = *(const bf16x8*)(ipwL + (size_t)(n0 + l15) * D_MODEL + quad * 8 + k0);
            acc = __builtin_amdgcn_mfma_f32_16x16x32_bf16(af, bw, acc, 0, 0, 0);
        }
        if (quad == 0) {
            #pragma unroll
            for (int r2 = 0; r2 < 3; r2++)
                xi_s[r2 * 512 + n0 + l15] = f2bf(acc[r2]);
        }
    }
    // ---- in_proj MFMA tile1: rows m0..m0+15, full n. n<512 -> xi, else zs --
    #pragma unroll
    for (int f = 0; f < 8; f++) {
        int n = w * 128 + f * 16 + l15;
        f32x4 acc = (f32x4){0.f, 0.f, 0.f, 0.f};
        for (int k0 = 0; k0 < D_MODEL; k0 += 32) {
            bf16x8 af = *(const bf16x8*)&hs[(3 + l15) * HS_STR + quad * 8 + k0];
            bf16x8 bw = *(const bf16x8*)(ipwL + (size_t)n * D_MODEL + quad * 8 + k0);
            acc = __builtin_amdgcn_mfma_f32_16x16x32_bf16(af, bw, acc, 0, 0, 0);
        }
        #pragma unroll
        for (int r2 = 0; r2 < 4; r2++) {
            int rl = quad * 4 + r2;
            if (n < 512) xi_s[(3 + rl) * 512 + n] = f2bf(acc[r2]);
            else zsB[(size_t)(m0 + rl) * D_INNER + (n - 512)] = f2bf(silu(acc[r2]));
        }
    }
    __syncthreads();

    // ---- conv(4) + SiLU -> xc_s + xcB. d = t ----
    {
        float4 cw4 = *(const float4*)(cwL + t * 4);
        float cbv = cbL[t];
        #pragma unroll
        for (int rl = 0; rl < 16; rl++) {
            int l = (m0 + rl) & (SEQLEN - 1);
            float s = cbv;
            if (l >= 3) s = fmaf(cw4.x, bf2f(xi_s[(rl + 0) * 512 + t]), s);
            if (l >= 2) s = fmaf(cw4.y, bf2f(xi_s[(rl + 1) * 512 + t]), s);
            if (l >= 1) s = fmaf(cw4.z, bf2f(xi_s[(rl + 2) * 512 + t]), s);
            s = fmaf(cw4.w, bf2f(xi_s[(rl + 3) * 512 + t]), s);
            ushort xcv = f2bf(silu(s));
            xc_s[rl * XC_STR + t] = xcv;
            xcB[(size_t)(m0 + rl) * D_INNER + t] = xcv;
        }
    }
    __syncthreads();

    // ---- x_proj MFMA (waves 0..2, one 16-n tile each) ----
    if (w < 3) {
        f32x4 acc = (f32x4){0.f, 0.f, 0.f, 0.f};
        for (int k0 = 0; k0 < D_INNER; k0 += 32) {
            bf16x8 af = *(const bf16x8*)&xc_s[l15 * XC_STR + quad * 8 + k0];
            bf16x8 bw = *(const bf16x8*)(xpwL + (size_t)(w * 16 + l15) * D_INNER + quad * 8 + k0);
            acc = __builtin_amdgcn_mfma_f32_16x16x32_bf16(af, bw, acc, 0, 0, 0);
        }
        int n = w * 16 + l15;
        #pragma unroll
        for (int r2 = 0; r2 < 4; r2++) {
            int rl = quad * 4 + r2;
            dbl_s[rl * 52 + n] = acc[r2];
            dbl[(size_t)(m0 + rl) * 48 + n] = acc[r2];
        }
    }
    __syncthreads();

    // ---- scan_sum (d = t), delta inline from dbl_s ----
    {
        float a[16], wdp[16];
        #pragma unroll
        for (int n = 0; n < 16; n++) a[n] = -__expf(alogL[(size_t)t * 16 + n]);
        *(float4*)&wdp[0]  = *(const float4*)(dpwL + (size_t)t * 16 + 0);
        *(float4*)&wdp[4]  = *(const float4*)(dpwL + (size_t)t * 16 + 4);
        *(float4*)&wdp[8]  = *(const float4*)(dpwL + (size_t)t * 16 + 8);
        *(float4*)&wdp[12] = *(const float4*)(dpwL + (size_t)t * 16 + 12);
        float bias = dpbL[t];
        float h[16];
        #pragma unroll
        for (int n = 0; n < 16; n++) h[n] = 0.f;
        float sd = 0.f;
        for (int j = 0; j < LCH; j++) {
            const float* dp = &dbl_s[j * 52];
            float dot = bias;
            #pragma unroll
            for (int r2 = 0; r2 < 16; r2++) dot = fmaf(dp[r2], wdp[r2], dot);
            float dl = (dot > 20.f) ? dot : log1pf(__expf(dot));
            float xv = bf2f(xc_s[j * XC_STR + t]);
            float u = dl * xv;
            sd += dl;
            #pragma unroll
            for (int n = 0; n < 16; n++)
                h[n] = fmaf(__expf(dl * a[n]), h[n], dp[16 + n] * u);
        }
        size_t sbase = ((size_t)bid * 16) * D_INNER + t;
        #pragma unroll
        for (int n = 0; n < 16; n++) Ssum[sbase + (size_t)n * D_INNER] = h[n];
        sdsum[(size_t)bid * D_INNER + t] = sd;
    }
}

// ---------------------------------------------------------------------------
// k_comb: in-place exclusive prefix over chunk summaries. Grid 64.
// ---------------------------------------------------------------------------
__global__ __launch_bounds__(256) void k_comb(
    const float* __restrict__ alogL, const float* __restrict__ sdsum,
    float* __restrict__ Ssum)
{
    const int t = threadIdx.x, bid = blockIdx.x;
    int dt2 = bid & 1;
    int n   = (bid >> 1) & 15;
    int b   = bid >> 5;
    int d   = dt2 * 256 + t;
    float a = -__expf(alogL[(size_t)d * 16 + n]);
    float hi = 0.f;
    #pragma unroll 4
    for (int c = 0; c < CCH; c++) {
        size_t idx = ((size_t)(b * CCH + c) * 16 + n) * D_INNER + d;
        float s  = Ssum[idx];
        float sd = sdsum[(size_t)(b * CCH + c) * D_INNER + d];
        Ssum[idx] = hi;
        hi = fmaf(__expf(a * sd), hi, s);
    }
}

// ---------------------------------------------------------------------------
// k_back: rescan from true h_init (delta inline) + D-skip + SiLU(z) gate,
//         yy kept in LDS, then out_proj MFMA + residual. Grid 256 x 512.
// ---------------------------------------------------------------------------
__global__ __launch_bounds__(512) void k_back(
    const float* __restrict__ dbl, const ushort* __restrict__ xcB,
    const ushort* __restrict__ zsB, const float* __restrict__ Ssum,
    const float* __restrict__ dpwL, const float* __restrict__ dpbL,
    const float* __restrict__ alogL, const float* __restrict__ dparL,
    const ushort* __restrict__ opwL, const float* __restrict__ xin,
    float* __restrict__ xout)
{
    const int t = threadIdx.x, bid = blockIdx.x;
    const int lane = t & 63, w = t >> 6, l15 = lane & 15, quad = lane >> 4;
    __shared__ ushort yy_s[16 * XC_STR];   // 16.6 KB
    int m0 = bid * 16;

    // ---- rescan, d = t ----
    {
        float a[16], wdp[16];
        #pragma unroll
        for (int n = 0; n < 16; n++) a[n] = -__expf(alogL[(size_t)t * 16 + n]);
        *(float4*)&wdp[0]  = *(const float4*)(dpwL + (size_t)t * 16 + 0);
        *(float4*)&wdp[4]  = *(const float4*)(dpwL + (size_t)t * 16 + 4);
        *(float4*)&wdp[8]  = *(const float4*)(dpwL + (size_t)t * 16 + 8);
        *(float4*)&wdp[12] = *(const float4*)(dpwL + (size_t)t * 16 + 12);
        float bias = dpbL[t];
        float Dd = dparL[t];
        float h[16];
        size_t sbase = ((size_t)bid * 16) * D_INNER + t;
        #pragma unroll
        for (int n = 0; n < 16; n++) h[n] = Ssum[sbase + (size_t)n * D_INNER];
        for (int j = 0; j < LCH; j++) {
            int row = m0 + j;
            const float* dp = dbl + (size_t)row * 48;
            float dtv[16], Bv[16], Cv[16];
            *(float4*)&dtv[0]  = *(const float4*)(dp + 0);
            *(float4*)&dtv[4]  = *(const float4*)(dp + 4);
            *(float4*)&dtv[8]  = *(const float4*)(dp + 8);
            *(float4*)&dtv[12] = *(const float4*)(dp + 12);
            *(float4*)&Bv[0]   = *(const float4*)(dp + 16);
            *(float4*)&Bv[4]   = *(const float4*)(dp + 20);
            *(float4*)&Bv[8]   = *(const float4*)(dp + 24);
            *(float4*)&Bv[12]  = *(const float4*)(dp + 28);
            *(float4*)&Cv[0]   = *(const float4*)(dp + 32);
            *(float4*)&Cv[4]   = *(const float4*)(dp + 36);
            *(float4*)&Cv[8]   = *(const float4*)(dp + 40);
            *(float4*)&Cv[12]  = *(const float4*)(dp + 44);
            float dot = bias;
            #pragma unroll
            for (int r2 = 0; r2 < 16; r2++) dot = fmaf(dtv[r2], wdp[r2], dot);
            float dl = (dot > 20.f) ? dot : log1pf(__expf(dot));
            float xv = bf2f(xcB[(size_t)row * D_INNER + t]);
            float gate = bf2f(zsB[(size_t)row * D_INNER + t]);
            float u = dl * xv;
            float y0 = 0.f, y1 = 0.f, y2 = 0.f, y3 = 0.f;
            #pragma unroll
            for (int n = 0; n < 16; n += 4) {
                h[n + 0] = fmaf(__expf(dl * a[n + 0]), h[n + 0], Bv[n + 0] * u);
                h[n + 1] = fmaf(__expf(dl * a[n + 1]), h[n + 1], Bv[n + 1] * u);
                h[n + 2] = fmaf(__expf(dl * a[n + 2]), h[n + 2], Bv[n + 2] * u);
                h[n + 3] = fmaf(__expf(dl * a[n + 3]), h[n + 3], Bv[n + 3] * u);
                y0 = fmaf(h[n + 0], Cv[n + 0], y0);
                y1 = fmaf(h[n + 1], Cv[n + 1], y1);
                y2 = fmaf(h[n + 2], Cv[n + 2], y2);
                y3 = fmaf(h[n + 3], Cv[n + 3], y3);
            }
            float y = (y0 + y1) + (y2 + y3) + xv * Dd;
            yy_s[j * XC_STR + t] = f2bf(y * gate);
        }
    }
    __syncthreads();

    // ---- out_proj MFMA + residual: wave w -> n-tiles w*32, w*32+16 ----
    #pragma unroll
    for (int f = 0; f < 2; f++) {
        int n = w * 32 + f * 16 + l15;
        f32x4 acc = (f32x4){0.f, 0.f, 0.f, 0.f};
        for (int k0 = 0; k0 < D_INNER; k0 += 32) {
            bf16x8 af = *(const bf16x8*)&yy_s[l15 * XC_STR + quad * 8 + k0];
            bf16x8 bw = *(const bf16x8*)(opwL + (size_t)n * D_INNER + quad * 8 + k0);
            acc = __builtin_amdgcn_mfma_f32_16x16x32_bf16(af, bw, acc, 0, 0, 0);
        }
        #pragma unroll
        for (int r2 = 0; r2 < 4; r2++) {
            int row = m0 + quad * 4 + r2;
            xout[(size_t)row * D_MODEL + n] =
                acc[r2] + xin[(size_t)row * D_MODEL + n];
        }
    }
}

// ---------------------------------------------------------------------------
// Launch
// ---------------------------------------------------------------------------
extern "C" void kernel_launch(void* const* d_in, const int* in_sizes, int n_in,
                              void* d_out, int out_size, void* d_ws, size_t ws_size,
                              hipStream_t stream)
{
    const float* x    = (const float*)d_in[0];
    const float* lnw  = (const float*)d_in[1];
    const float* lnb  = (const float*)d_in[2];
    const float* ipw  = (const float*)d_in[3];
    const float* cw   = (const float*)d_in[4];
    const float* cb   = (const float*)d_in[5];
    const float* xpw  = (const float*)d_in[6];
    const float* dpw  = (const float*)d_in[7];
    const float* dpb  = (const float*)d_in[8];
    const float* alog = (const float*)d_in[9];
    const float* dpar = (const float*)d_in[10];
    const float* opw  = (const float*)d_in[11];
    float* out = (float*)d_out;

    char* p = (char*)d_ws;
    auto alloc = [&](size_t bytes) { char* r = p; p += (bytes + 255) & ~(size_t)255; return r; };
    ushort* zsB   = (ushort*)alloc((size_t)MROWS * D_INNER * 2);
    ushort* xcB   = (ushort*)alloc((size_t)MROWS * D_INNER * 2);
    float*  dbl   = (float*)alloc((size_t)MROWS * 48 * 4);
    float*  Ssum  = (float*)alloc((size_t)BATCH * CCH * 16 * D_INNER * 4);
    float*  sdsum = (float*)alloc((size_t)BATCH * CCH * D_INNER * 4);
    float*  xbuf  = (float*)alloc((size_t)MROWS * D_MODEL * 4);
    ushort* ipwB  = (ushort*)alloc((size_t)DEPTH * 2 * D_INNER * D_MODEL * 2);
    ushort* xpwB  = (ushort*)alloc((size_t)DEPTH * 48 * D_INNER * 2);
    ushort* opwB  = (ushort*)alloc((size_t)DEPTH * D_MODEL * D_INNER * 2);

    k_cvt<<<512, 256, 0, stream>>>(ipw, xpw, opw, ipwB, xpwB, opwB);

    for (int lyr = 0; lyr < DEPTH; lyr++) {
        const float* xin = (lyr == 0) ? x : xbuf;
        float* xout = (lyr == DEPTH - 1) ? out : xbuf;
        const float* alogL = alog + (size_t)lyr * D_INNER * D_STATE;
        const float* dpwL  = dpw + (size_t)lyr * D_INNER * DT_RANK;
        const float* dpbL  = dpb + lyr * D_INNER;

        k_front<<<256, 512, 0, stream>>>(
            xin, lnw + lyr * D_MODEL, lnb + lyr * D_MODEL,
            ipwB + (size_t)lyr * 2 * D_INNER * D_MODEL,
            cw + (size_t)lyr * D_INNER * D_CONV, cb + lyr * D_INNER,
            xpwB + (size_t)lyr * 48 * D_INNER, dpwL, dpbL, alogL,
            zsB, xcB, dbl, Ssum, sdsum);

        k_comb<<<64, 256, 0, stream>>>(alogL, sdsum, Ssum);

        k_back<<<256, 512, 0, stream>>>(
            dbl, xcB, zsB, Ssum, dpwL, dpbL, alogL,
            dpar + lyr * D_INNER,
            opwB + (size_t)lyr * D_MODEL * D_INNER, xin, xout);
    }
}